// Round 13
// baseline (82.059 us; speedup 1.0000x reference)
//
#include <hip/hip_runtime.h>
#include <hip/hip_bf16.h>
#include <math.h>

// MemoryReader: B=16 H=8 M=64 K=32 R=65536 D_IN=512, OUT_DIM=520
// Outputs (FLOAT32, concatenated): flat_reads[16,512] | read_weights[16,8,32] |
//                                  read_indices[16,8,32] | read_strengths[16,8]

#define NB 16
#define NH 8
#define NM 64
#define NK 32
#define NR 65536
#define NDIN 512
#define NOUT 520
#define CHUNK 512
#define NCHUNK 128      // R / CHUNK
#define CAND 48         // candidate slots per (chunk, head); count target in [NK, CAND]
#define NCTOT (NCHUNK * CAND)   // 6144 candidates per (b,h)
#define FPT (NCTOT / 256)       // 24 per thread in k_final
#define STAGE1 (4 * CAND)       // 192 stage-1 survivors in k_final
#define SCP 516                 // sc stride: 4h+g banks all distinct -> conflict-free

#define OFF_READS 0
#define OFF_W 8192
#define OFF_I 12288
#define OFF_S 16384

typedef float floatx4 __attribute__((ext_vector_type(4)));

__device__ __forceinline__ float dot4(float4 a, float4 b) {
  return a.x * b.x + a.y * b.y + a.z * b.z + a.w * b.w;
}
__device__ __forceinline__ float dot4v(floatx4 a, float4 b) {
  return a.x * b.x + a.y * b.y + a.z * b.z + a.w * b.w;
}
__device__ __forceinline__ float dot4vv(floatx4 a, floatx4 b) {
  return a.x * b.x + a.y * b.y + a.z * b.z + a.w * b.w;
}
// non-temporal 16B load via native clang vector type (float4 is rejected)
__device__ __forceinline__ floatx4 ntload4(const float4* p) {
  return __builtin_nontemporal_load(reinterpret_cast<const floatx4*>(p));
}

// ---- DPP cross-lane helpers (VALU pipe, zero DS-pipe traffic) ----
// quad_perm 0xB1 = xor-1, 0x4E = xor-2, 0x104/0x114 = row_shl:4/row_shr:4,
// 0x124/0x128 = row_ror:4 / row_ror:8 (ror8 == exact xor-8 within row16).
template <int CTRL>
__device__ __forceinline__ float dppf(float x) {
  return __int_as_float(__builtin_amdgcn_update_dpp(
      0, __float_as_int(x), CTRL, 0xF, 0xF, true));
}
template <int CTRL>
__device__ __forceinline__ int dppi(int x) {
  return __builtin_amdgcn_update_dpp(0, x, CTRL, 0xF, 0xF, true);
}
__device__ __forceinline__ float rdlf(float x, int l) {
  return __int_as_float(__builtin_amdgcn_readlane(__float_as_int(x), l));
}
__device__ __forceinline__ float wmax64(float x) {
  x = fmaxf(x, dppf<0xB1>(x));
  x = fmaxf(x, dppf<0x4E>(x));
  x = fmaxf(x, dppf<0x124>(x));
  x = fmaxf(x, dppf<0x128>(x));
  return fmaxf(fmaxf(rdlf(x, 0), rdlf(x, 16)), fmaxf(rdlf(x, 32), rdlf(x, 48)));
}
__device__ __forceinline__ float wmin64(float x) {
  x = fminf(x, dppf<0xB1>(x));
  x = fminf(x, dppf<0x4E>(x));
  x = fminf(x, dppf<0x124>(x));
  x = fminf(x, dppf<0x128>(x));
  return fminf(fminf(rdlf(x, 0), rdlf(x, 16)), fminf(rdlf(x, 32), rdlf(x, 48)));
}
__device__ __forceinline__ unsigned wsum64u(unsigned c) {
  int x = (int)c;
  x += dppi<0xB1>(x);
  x += dppi<0x4E>(x);
  x += dppi<0x124>(x);
  x += dppi<0x128>(x);
  return (unsigned)(__builtin_amdgcn_readlane(x, 0) + __builtin_amdgcn_readlane(x, 16) +
                    __builtin_amdgcn_readlane(x, 32) + __builtin_amdgcn_readlane(x, 48));
}

// Kernel 1: flat = x @ W^T + b, split over (b, head) blocks; 512 threads so
// each thread's serial load chain is 4 dwordx4 (was 8) — latency-bound kernel.
__global__ __launch_bounds__(512) void k_prep(
    const float* __restrict__ x, const float* __restrict__ W,
    const float* __restrict__ bias, float* __restrict__ sk_ws,
    float* __restrict__ str_ws, float* __restrict__ dout) {
  const int blk = blockIdx.x;          // 0..143
  const int b = blk / 9, h = blk % 9;  // h==8: strengths block
  const int t = threadIdx.x;           // 512 threads
  __shared__ float4 xs4[NDIN / 4];
  __shared__ float flat64[NM];
  if (t < 128) xs4[t] = reinterpret_cast<const float4*>(x + (size_t)b * NDIN)[t];
  __syncthreads();
  if (h < 8) {
    // 64 outputs, 8 threads each over 64 contiguous floats
    const int j = h * 64 + (t >> 3);
    const int p = t & 7;
    const float4* Wr = reinterpret_cast<const float4*>(W + (size_t)j * NDIN);
    float acc = 0.f;
    #pragma unroll 4
    for (int i = p * 16; i < p * 16 + 16; ++i) acc += dot4(Wr[i], xs4[i]);
    acc += __shfl_xor(acc, 1, 64);
    acc += __shfl_xor(acc, 2, 64);
    acc += __shfl_xor(acc, 4, 64);
    if (p == 0) flat64[t >> 3] = acc + bias[j];
    __syncthreads();
    if (t < 64) {  // wave 0: normalize this head's 64 keys
      float v = flat64[t];
      float ss = v * v;
      #pragma unroll
      for (int off = 32; off >= 1; off >>= 1) ss += __shfl_xor(ss, off, 64);
      float rn = 1.0f / fmaxf(sqrtf(ss), 1e-12f);
      sk_ws[(size_t)b * NDIN + h * 64 + t] = v * rn;
    }
  } else {
    // 8 strength outputs, one wave each
    const int j = NDIN + (t >> 6);
    const int p = t & 63;
    const float4* Wr = reinterpret_cast<const float4*>(W + (size_t)j * NDIN);
    float acc = 0.f;
    acc += dot4(Wr[p * 2], xs4[p * 2]);
    acc += dot4(Wr[p * 2 + 1], xs4[p * 2 + 1]);
    #pragma unroll
    for (int off = 32; off >= 1; off >>= 1) acc += __shfl_xor(acc, off, 64);
    if (p == 0) {
      float s = acc + bias[j];
      str_ws[b * NH + (t >> 6)] = s;
      dout[OFF_S + b * NH + (t >> 6)] = s;
    }
  }
}

// Kernel 2: per (b, 512-row chunk). R8 structure (known-best 79.6 us) with ONE
// isolated change: NON-TEMPORAL loads on the mem stream. 268 MB single-use
// data streaming through 4-MiB L2s causes allocate-evict churn on every line;
// nt marks the stream evict-first so the read path stops paying allocation
// overhead. Everything else identical to R8: coalesced 4-batched float4
// loads, DPP-only reduce tree (1 ds_write/KiB), per-wave shfl-free selection.
__global__ __launch_bounds__(512, 6) void k_score(
    const float* __restrict__ mem, const float* __restrict__ sk_ws,
    const float* __restrict__ str_ws, float* __restrict__ cv_ws,
    unsigned* __restrict__ ci_ws) {
  const int b = blockIdx.x >> 7;
  const int chunk = blockIdx.x & 127;
  const int base = chunk * CHUNK;
  const int t = threadIdx.x;
  const int lane = t & 63, w = t >> 6;  // 8 waves

  __shared__ float sc_f[NH * SCP];      // 16.5 KB, stride 516
  __shared__ float4 sk4[NH * 16];       // 2 KB
  __shared__ float str_s[NH];
  __shared__ float candv[NH][CAND];
  __shared__ unsigned candi[NH][CAND];
  __shared__ unsigned cnt_s[NH];

  if (t < 128) sk4[t] = reinterpret_cast<const float4*>(sk_ws + (size_t)b * NDIN)[t];
  if (t < NH) str_s[t] = str_ws[b * NH + t];
  __syncthreads();

  // per-lane preload: seg s of all 8 heads' keys (32 VGPR), + this lane's head
  const int s = lane & 15;
  const float4 k0 = sk4[0 * 16 + s], k1 = sk4[1 * 16 + s];
  const float4 k2 = sk4[2 * 16 + s], k3 = sk4[3 * 16 + s];
  const float4 k4 = sk4[4 * 16 + s], k5 = sk4[5 * 16 + s];
  const float4 k6 = sk4[6 * 16 + s], k7 = sk4[7 * 16 + s];
  const int hl = ((lane & 1) << 2) | (lane & 2) | ((lane >> 2) & 1);
  const float str_l = str_s[hl];
  const int g = lane >> 4;
  float* myslot = &sc_f[hl * SCP + w * 64 + g];

  const float4* mem4 =
      reinterpret_cast<const float4*>(mem + ((size_t)b * NR + base + w * 64) * NM);

  // one row-quad's full reduce chain — all cross-lane via DPP (VALU pipe)
  auto process = [&](floatx4 va, int i) {
    float ss = dot4vv(va, va);
    float a0 = dot4v(va, k0), a1 = dot4v(va, k1), a2 = dot4v(va, k2), a3 = dot4v(va, k3);
    float a4 = dot4v(va, k4), a5 = dot4v(va, k5), a6 = dot4v(va, k6), a7 = dot4v(va, k7);
    ss += dppf<0xB1>(ss);
    ss += dppf<0x4E>(ss);
    ss += dppf<0x124>(ss);
    ss += dppf<0x128>(ss);
    // head bit2 <- lane bit0 (exact xor-1)
    {
      const bool bit = (lane & 1) != 0;
      float s0 = bit ? a0 : a4, p0 = bit ? a4 : a0;
      float s1 = bit ? a1 : a5, p1 = bit ? a5 : a1;
      float s2 = bit ? a2 : a6, p2 = bit ? a6 : a2;
      float s3 = bit ? a3 : a7, p3 = bit ? a7 : a3;
      a0 = p0 + dppf<0xB1>(s0);
      a1 = p1 + dppf<0xB1>(s1);
      a2 = p2 + dppf<0xB1>(s2);
      a3 = p3 + dppf<0xB1>(s3);
    }
    // head bit1 <- lane bit1 (exact xor-2)
    {
      const bool bit = (lane & 2) != 0;
      float s0 = bit ? a0 : a2, p0 = bit ? a2 : a0;
      float s1 = bit ? a1 : a3, p1 = bit ? a3 : a1;
      a0 = p0 + dppf<0x4E>(s0);
      a1 = p1 + dppf<0x4E>(s1);
    }
    // head bit0 <- lane bit2 (exact xor-4 via shl/shr + select)
    {
      const bool bit = (lane & 4) != 0;
      float s0 = bit ? a0 : a1, p0 = bit ? a1 : a0;
      float xlo = dppf<0x104>(s0);
      float xhi = dppf<0x114>(s0);
      a0 = p0 + (bit ? xhi : xlo);
    }
    a0 += dppf<0x128>(a0);  // combine halves: row_ror:8 == exact xor-8 in row16
    float rn = 1.0f / fmaxf(sqrtf(ss), 1e-12f);
    myslot[4 * i] = str_l * (a0 * rn);  // lanes l and l^8: same addr, free
  };

  // ---- score phase: 4 batched NON-TEMPORAL loads per step ----
  #pragma unroll
  for (int ib = 0; ib < 4; ++ib) {
    floatx4 va0 = ntload4(&mem4[(4 * ib + 0) * 64 + lane]);
    floatx4 va1 = ntload4(&mem4[(4 * ib + 1) * 64 + lane]);
    floatx4 va2 = ntload4(&mem4[(4 * ib + 2) * 64 + lane]);
    floatx4 va3 = ntload4(&mem4[(4 * ib + 3) * 64 + lane]);
    process(va0, 4 * ib + 0);
    process(va1, 4 * ib + 1);
    process(va2, 4 * ib + 2);
    process(va3, 4 * ib + 3);
  }
  __syncthreads();  // the only selection-relevant block barrier

  // ---- selection: wave w handles head w, fully wave-private ----
  {
    const int h = w;
    float v[8];
    #pragma unroll
    for (int j = 0; j < 8; ++j) v[j] = sc_f[h * SCP + lane + 64 * j];

    float mxl = v[0], mnl = v[0];
    #pragma unroll
    for (int j = 1; j < 8; ++j) { mxl = fmaxf(mxl, v[j]); mnl = fminf(mnl, v[j]); }
    float mx = wmax64(mxl);
    float mn = wmin64(mnl);

    // binary search for T with count(>T) in [NK, CAND] — DPP+readlane, 0 DS
    float lo = mn - 1.0f, hi = mx, T = lo;
    bool found = false;
    for (int it = 0; it < 48; ++it) {
      float mid = 0.5f * (lo + hi);
      if (!(mid > lo && mid < hi)) break;
      unsigned c = 0;
      #pragma unroll
      for (int j = 0; j < 8; ++j) c += (v[j] > mid) ? 1u : 0u;
      c = wsum64u(c);
      if (c >= NK) {
        lo = mid;
        if (c <= CAND) { T = mid; found = true; break; }
      } else {
        hi = mid;
      }
    }
    if (!found) T = lo;  // invariant: count(>lo) >= NK

    if (lane == 0) cnt_s[h] = 0u;
    // same-wave LDS ordering: write above precedes the atomics below
    #pragma unroll
    for (int j = 0; j < 8; ++j) {
      if (v[j] > T) {
        unsigned p = atomicAdd(&cnt_s[h], 1u);
        if (p < CAND) { candv[h][p] = v[j]; candi[h][p] = (unsigned)(base + lane + 64 * j); }
      }
    }
    unsigned c = cnt_s[h];
    for (unsigned p = c + (unsigned)lane; p < CAND; p += 64u) {
      candv[h][p] = -INFINITY; candi[h][p] = 0x7F000000u + p;
    }
    if (lane < CAND) {
      size_t o = (((size_t)(b * NH + h)) * NCHUNK + chunk) * CAND + lane;
      cv_ws[o] = candv[h][lane];
      ci_ws[o] = candi[h][lane];
    }
  }
}

// Kernel 3: per (b,h): stage-1 per-wave top-[32,48] supersets (shfl-only),
// stage-2 rank-based exact sorted top-32 over <=192 survivors, then softmax +
// gather. (known-good since R4)
__global__ __launch_bounds__(256) void k_final(
    const float* __restrict__ mem, const float* __restrict__ cv_ws,
    const unsigned* __restrict__ ci_ws, float* __restrict__ dout) {
  const int bh = blockIdx.x;
  const int b = bh >> 3;
  const int t = threadIdx.x;
  const int lane = t & 63, w = t >> 6;  // 4 waves

  __shared__ float cv[STAGE1];
  __shared__ unsigned ci[STAGE1];
  __shared__ unsigned cnt_s[4];
  __shared__ float fv[NK];
  __shared__ unsigned fi[NK];
  __shared__ float wts[NK];
  __shared__ unsigned widx[NK];

  const float* CV = cv_ws + (size_t)bh * NCTOT;
  const unsigned* CI = ci_ws + (size_t)bh * NCTOT;

  float v[FPT];
  unsigned vi[FPT];
  #pragma unroll
  for (int i = 0; i < FPT; ++i) {
    v[i] = CV[i * 256 + t];
    vi[i] = CI[i * 256 + t];
  }

  // wave-local range (exclude -INF pads from min)
  float mx = -INFINITY, mn = INFINITY;
  #pragma unroll
  for (int i = 0; i < FPT; ++i) {
    mx = fmaxf(mx, v[i]);
    if (v[i] > -1e37f) mn = fminf(mn, v[i]);
  }
  #pragma unroll
  for (int off = 32; off >= 1; off >>= 1) {
    mx = fmaxf(mx, __shfl_xor(mx, off, 64));
    mn = fminf(mn, __shfl_xor(mn, off, 64));
  }

  // wave-local binary search: count(>T) in [NK, CAND] over this wave's 1536
  float lo = mn - 1.0f, hi = mx, T = lo;
  bool found = false;
  for (int it = 0; it < 48; ++it) {
    float mid = 0.5f * (lo + hi);
    if (!(mid > lo && mid < hi)) break;
    unsigned c = 0;
    #pragma unroll
    for (int i = 0; i < FPT; ++i) c += (v[i] > mid) ? 1u : 0u;
    #pragma unroll
    for (int off = 32; off >= 1; off >>= 1) c += __shfl_xor(c, off, 64);
    if (c >= NK) {
      lo = mid;
      if (c <= CAND) { T = mid; found = true; break; }
    } else {
      hi = mid;
    }
  }
  if (!found) T = lo;

  if (lane == 0) cnt_s[w] = 0u;
  #pragma unroll
  for (int i = 0; i < FPT; ++i) {
    if (v[i] > T) {
      unsigned p = atomicAdd(&cnt_s[w], 1u);
      if (p < CAND) { cv[w * CAND + p] = v[i]; ci[w * CAND + p] = vi[i]; }
    }
  }
  {
    unsigned c = cnt_s[w];
    for (unsigned p = c + (unsigned)lane; p < CAND; p += 64u) {
      cv[w * CAND + p] = -INFINITY;
      ci[w * CAND + p] = 0x7F100000u + w * CAND + p;
    }
  }
  __syncthreads();

  // stage 2: exact rank (val desc, idx asc); top-32 land sorted in fv/fi
  if (t < STAGE1) {
    float myv = cv[t];
    unsigned myi = ci[t];
    int rank = 0;
    for (int j = 0; j < STAGE1; ++j) {
      float vj = cv[j];
      unsigned ij = ci[j];
      rank += ((vj > myv) || (vj == myv && ij < myi)) ? 1 : 0;
    }
    if (rank < NK) { fv[rank] = myv; fi[rank] = myi; }
  }
  __syncthreads();

  // softmax over the sorted top-32 (fv[0] is the max)
  if (t < NK) {
    float e = expf(fv[t] - fv[0]);
    float sum = e;
    #pragma unroll
    for (int off = 16; off >= 1; off >>= 1) sum += __shfl_xor(sum, off, 32);
    float wgt = e / sum;
    wts[t] = wgt;
    widx[t] = fi[t];
    dout[OFF_W + bh * NK + t] = wgt;
    dout[OFF_I + bh * NK + t] = (float)fi[t];
  }
  __syncthreads();

  // memory_reads[b,h,m] = sum_k w_k * mem[b, idx_k, m]
  if (t < NM) {
    float acc = 0.f;
    #pragma unroll 8
    for (int k = 0; k < NK; ++k) {
      unsigned gi = widx[k] < NR ? widx[k] : 0u;  // defensive clamp
      acc += wts[k] * mem[((size_t)b * NR + gi) * NM + t];
    }
    dout[OFF_READS + bh * NM + t] = acc;
  }
}

extern "C" void kernel_launch(void* const* d_in, const int* in_sizes, int n_in,
                              void* d_out, int out_size, void* d_ws, size_t ws_size,
                              hipStream_t stream) {
  const float* x    = (const float*)d_in[0];  // read_inputs (16,512)
  const float* mem  = (const float*)d_in[1];  // mem_state (16,65536,64)
  const float* W    = (const float*)d_in[2];  // (520,512)
  const float* bias = (const float*)d_in[3];  // (520,)
  float* out = (float*)d_out;

  char* ws = (char*)d_ws;
  float* sk_ws    = (float*)ws;                   // 32 KB
  float* str_ws   = (float*)(ws + 32768);         // 512 B
  const size_t cand_bytes = (size_t)NB * NH * NCTOT * 4;  // 3.15 MB
  float* cv_ws    = (float*)(ws + 65536);
  unsigned* ci_ws = (unsigned*)(ws + 65536 + cand_bytes);

  hipLaunchKernelGGL(k_prep, dim3(NB * 9), dim3(512), 0, stream, x, W, bias, sk_ws, str_ws, out);
  hipLaunchKernelGGL(k_score, dim3(NB * NCHUNK), dim3(512), 0, stream, mem, sk_ws, str_ws, cv_ws, ci_ws);
  hipLaunchKernelGGL(k_final, dim3(NB * NH), dim3(256), 0, stream, mem, cv_ws, ci_ws, out);
}

// Round 14
// 79.666 us; speedup vs baseline: 1.0300x; 1.0300x over previous
//
#include <hip/hip_runtime.h>
#include <hip/hip_bf16.h>
#include <math.h>

// MemoryReader: B=16 H=8 M=64 K=32 R=65536 D_IN=512, OUT_DIM=520
// Outputs (FLOAT32, concatenated): flat_reads[16,512] | read_weights[16,8,32] |
//                                  read_indices[16,8,32] | read_strengths[16,8]
//
// Final structure (R8-consolidated):
//  k_prep : (b,head)-split GEMM + key normalize, 512 thr (short load chains)
//  k_score: per (b,512-row chunk), coalesced float4 stream + DPP-only
//           reduce/transpose tree (1 ds_write/KiB), per-wave shfl-free
//           threshold selection -> <=48 candidates/chunk/head
//  k_final: exact global top-32 (binary search + rank), softmax, gather
// Wall: ~4.1 TB/s effective read path (7 orthogonal probes null at ~80us).

#define NB 16
#define NH 8
#define NM 64
#define NK 32
#define NR 65536
#define NDIN 512
#define NOUT 520
#define CHUNK 512
#define NCHUNK 128      // R / CHUNK
#define CAND 48         // candidate slots per (chunk, head); count target in [NK, CAND]
#define NCTOT (NCHUNK * CAND)   // 6144 candidates per (b,h)
#define FPT (NCTOT / 256)       // 24 per thread in k_final
#define STAGE1 (4 * CAND)       // 192 stage-1 survivors in k_final
#define SCP 516                 // sc stride: 4h+g banks all distinct -> conflict-free

#define OFF_READS 0
#define OFF_W 8192
#define OFF_I 12288
#define OFF_S 16384

__device__ __forceinline__ float dot4(float4 a, float4 b) {
  return a.x * b.x + a.y * b.y + a.z * b.z + a.w * b.w;
}

// ---- DPP cross-lane helpers (VALU pipe, zero DS-pipe traffic) ----
// quad_perm 0xB1 = xor-1, 0x4E = xor-2, 0x104/0x114 = row_shl:4/row_shr:4,
// 0x124/0x128 = row_ror:4 / row_ror:8 (ror8 == exact xor-8 within row16).
template <int CTRL>
__device__ __forceinline__ float dppf(float x) {
  return __int_as_float(__builtin_amdgcn_update_dpp(
      0, __float_as_int(x), CTRL, 0xF, 0xF, true));
}
template <int CTRL>
__device__ __forceinline__ int dppi(int x) {
  return __builtin_amdgcn_update_dpp(0, x, CTRL, 0xF, 0xF, true);
}
__device__ __forceinline__ float rdlf(float x, int l) {
  return __int_as_float(__builtin_amdgcn_readlane(__float_as_int(x), l));
}
__device__ __forceinline__ float wmax64(float x) {
  x = fmaxf(x, dppf<0xB1>(x));
  x = fmaxf(x, dppf<0x4E>(x));
  x = fmaxf(x, dppf<0x124>(x));
  x = fmaxf(x, dppf<0x128>(x));
  return fmaxf(fmaxf(rdlf(x, 0), rdlf(x, 16)), fmaxf(rdlf(x, 32), rdlf(x, 48)));
}
__device__ __forceinline__ float wmin64(float x) {
  x = fminf(x, dppf<0xB1>(x));
  x = fminf(x, dppf<0x4E>(x));
  x = fminf(x, dppf<0x124>(x));
  x = fminf(x, dppf<0x128>(x));
  return fminf(fminf(rdlf(x, 0), rdlf(x, 16)), fminf(rdlf(x, 32), rdlf(x, 48)));
}
__device__ __forceinline__ unsigned wsum64u(unsigned c) {
  int x = (int)c;
  x += dppi<0xB1>(x);
  x += dppi<0x4E>(x);
  x += dppi<0x124>(x);
  x += dppi<0x128>(x);
  return (unsigned)(__builtin_amdgcn_readlane(x, 0) + __builtin_amdgcn_readlane(x, 16) +
                    __builtin_amdgcn_readlane(x, 32) + __builtin_amdgcn_readlane(x, 48));
}

// Kernel 1: flat = x @ W^T + b, split over (b, head) blocks; 512 threads so
// each thread's serial load chain is 4 dwordx4 — latency-bound kernel.
__global__ __launch_bounds__(512) void k_prep(
    const float* __restrict__ x, const float* __restrict__ W,
    const float* __restrict__ bias, float* __restrict__ sk_ws,
    float* __restrict__ str_ws, float* __restrict__ dout) {
  const int blk = blockIdx.x;          // 0..143
  const int b = blk / 9, h = blk % 9;  // h==8: strengths block
  const int t = threadIdx.x;           // 512 threads
  __shared__ float4 xs4[NDIN / 4];
  __shared__ float flat64[NM];
  if (t < 128) xs4[t] = reinterpret_cast<const float4*>(x + (size_t)b * NDIN)[t];
  __syncthreads();
  if (h < 8) {
    // 64 outputs, 8 threads each over 64 contiguous floats
    const int j = h * 64 + (t >> 3);
    const int p = t & 7;
    const float4* Wr = reinterpret_cast<const float4*>(W + (size_t)j * NDIN);
    float acc = 0.f;
    #pragma unroll 4
    for (int i = p * 16; i < p * 16 + 16; ++i) acc += dot4(Wr[i], xs4[i]);
    acc += __shfl_xor(acc, 1, 64);
    acc += __shfl_xor(acc, 2, 64);
    acc += __shfl_xor(acc, 4, 64);
    if (p == 0) flat64[t >> 3] = acc + bias[j];
    __syncthreads();
    if (t < 64) {  // wave 0: normalize this head's 64 keys
      float v = flat64[t];
      float ss = v * v;
      #pragma unroll
      for (int off = 32; off >= 1; off >>= 1) ss += __shfl_xor(ss, off, 64);
      float rn = 1.0f / fmaxf(sqrtf(ss), 1e-12f);
      sk_ws[(size_t)b * NDIN + h * 64 + t] = v * rn;
    }
  } else {
    // 8 strength outputs, one wave each
    const int j = NDIN + (t >> 6);
    const int p = t & 63;
    const float4* Wr = reinterpret_cast<const float4*>(W + (size_t)j * NDIN);
    float acc = 0.f;
    acc += dot4(Wr[p * 2], xs4[p * 2]);
    acc += dot4(Wr[p * 2 + 1], xs4[p * 2 + 1]);
    #pragma unroll
    for (int off = 32; off >= 1; off >>= 1) acc += __shfl_xor(acc, off, 64);
    if (p == 0) {
      float s = acc + bias[j];
      str_ws[b * NH + (t >> 6)] = s;
      dout[OFF_S + b * NH + (t >> 6)] = s;
    }
  }
}

// Kernel 2: per (b, 512-row chunk). Known-best R8 structure: coalesced
// 4-batched float4 loads (normal, L3-allocating), DPP-only reduce tree
// (1 ds_write/KiB on the DS pipe), per-wave DPP+readlane selection.
__global__ __launch_bounds__(512, 6) void k_score(
    const float* __restrict__ mem, const float* __restrict__ sk_ws,
    const float* __restrict__ str_ws, float* __restrict__ cv_ws,
    unsigned* __restrict__ ci_ws) {
  const int b = blockIdx.x >> 7;
  const int chunk = blockIdx.x & 127;
  const int base = chunk * CHUNK;
  const int t = threadIdx.x;
  const int lane = t & 63, w = t >> 6;  // 8 waves

  __shared__ float sc_f[NH * SCP];      // 16.5 KB, stride 516
  __shared__ float4 sk4[NH * 16];       // 2 KB
  __shared__ float str_s[NH];
  __shared__ float candv[NH][CAND];
  __shared__ unsigned candi[NH][CAND];
  __shared__ unsigned cnt_s[NH];

  if (t < 128) sk4[t] = reinterpret_cast<const float4*>(sk_ws + (size_t)b * NDIN)[t];
  if (t < NH) str_s[t] = str_ws[b * NH + t];
  __syncthreads();

  // per-lane preload: seg s of all 8 heads' keys (32 VGPR), + this lane's head
  const int s = lane & 15;
  const float4 k0 = sk4[0 * 16 + s], k1 = sk4[1 * 16 + s];
  const float4 k2 = sk4[2 * 16 + s], k3 = sk4[3 * 16 + s];
  const float4 k4 = sk4[4 * 16 + s], k5 = sk4[5 * 16 + s];
  const float4 k6 = sk4[6 * 16 + s], k7 = sk4[7 * 16 + s];
  const int hl = ((lane & 1) << 2) | (lane & 2) | ((lane >> 2) & 1);
  const float str_l = str_s[hl];
  const int g = lane >> 4;
  float* myslot = &sc_f[hl * SCP + w * 64 + g];

  const float4* mem4 =
      reinterpret_cast<const float4*>(mem + ((size_t)b * NR + base + w * 64) * NM);

  // one row-quad's full reduce chain — all cross-lane via DPP (VALU pipe)
  auto process = [&](float4 va, int i) {
    float ss = dot4(va, va);
    float a0 = dot4(va, k0), a1 = dot4(va, k1), a2 = dot4(va, k2), a3 = dot4(va, k3);
    float a4 = dot4(va, k4), a5 = dot4(va, k5), a6 = dot4(va, k6), a7 = dot4(va, k7);
    ss += dppf<0xB1>(ss);
    ss += dppf<0x4E>(ss);
    ss += dppf<0x124>(ss);
    ss += dppf<0x128>(ss);
    // head bit2 <- lane bit0 (exact xor-1)
    {
      const bool bit = (lane & 1) != 0;
      float s0 = bit ? a0 : a4, p0 = bit ? a4 : a0;
      float s1 = bit ? a1 : a5, p1 = bit ? a5 : a1;
      float s2 = bit ? a2 : a6, p2 = bit ? a6 : a2;
      float s3 = bit ? a3 : a7, p3 = bit ? a7 : a3;
      a0 = p0 + dppf<0xB1>(s0);
      a1 = p1 + dppf<0xB1>(s1);
      a2 = p2 + dppf<0xB1>(s2);
      a3 = p3 + dppf<0xB1>(s3);
    }
    // head bit1 <- lane bit1 (exact xor-2)
    {
      const bool bit = (lane & 2) != 0;
      float s0 = bit ? a0 : a2, p0 = bit ? a2 : a0;
      float s1 = bit ? a1 : a3, p1 = bit ? a3 : a1;
      a0 = p0 + dppf<0x4E>(s0);
      a1 = p1 + dppf<0x4E>(s1);
    }
    // head bit0 <- lane bit2 (exact xor-4 via shl/shr + select)
    {
      const bool bit = (lane & 4) != 0;
      float s0 = bit ? a0 : a1, p0 = bit ? a1 : a0;
      float xlo = dppf<0x104>(s0);
      float xhi = dppf<0x114>(s0);
      a0 = p0 + (bit ? xhi : xlo);
    }
    a0 += dppf<0x128>(a0);  // combine halves: row_ror:8 == exact xor-8 in row16
    float rn = 1.0f / fmaxf(sqrtf(ss), 1e-12f);
    myslot[4 * i] = str_l * (a0 * rn);  // lanes l and l^8: same addr, free
  };

  // ---- score phase: 4 batched loads per step ----
  #pragma unroll
  for (int ib = 0; ib < 4; ++ib) {
    float4 va0 = mem4[(4 * ib + 0) * 64 + lane];
    float4 va1 = mem4[(4 * ib + 1) * 64 + lane];
    float4 va2 = mem4[(4 * ib + 2) * 64 + lane];
    float4 va3 = mem4[(4 * ib + 3) * 64 + lane];
    process(va0, 4 * ib + 0);
    process(va1, 4 * ib + 1);
    process(va2, 4 * ib + 2);
    process(va3, 4 * ib + 3);
  }
  __syncthreads();  // the only selection-relevant block barrier

  // ---- selection: wave w handles head w, fully wave-private ----
  {
    const int h = w;
    float v[8];
    #pragma unroll
    for (int j = 0; j < 8; ++j) v[j] = sc_f[h * SCP + lane + 64 * j];

    float mxl = v[0], mnl = v[0];
    #pragma unroll
    for (int j = 1; j < 8; ++j) { mxl = fmaxf(mxl, v[j]); mnl = fminf(mnl, v[j]); }
    float mx = wmax64(mxl);
    float mn = wmin64(mnl);

    // binary search for T with count(>T) in [NK, CAND] — DPP+readlane, 0 DS
    float lo = mn - 1.0f, hi = mx, T = lo;
    bool found = false;
    for (int it = 0; it < 48; ++it) {
      float mid = 0.5f * (lo + hi);
      if (!(mid > lo && mid < hi)) break;
      unsigned c = 0;
      #pragma unroll
      for (int j = 0; j < 8; ++j) c += (v[j] > mid) ? 1u : 0u;
      c = wsum64u(c);
      if (c >= NK) {
        lo = mid;
        if (c <= CAND) { T = mid; found = true; break; }
      } else {
        hi = mid;
      }
    }
    if (!found) T = lo;  // invariant: count(>lo) >= NK

    if (lane == 0) cnt_s[h] = 0u;
    // same-wave LDS ordering: write above precedes the atomics below
    #pragma unroll
    for (int j = 0; j < 8; ++j) {
      if (v[j] > T) {
        unsigned p = atomicAdd(&cnt_s[h], 1u);
        if (p < CAND) { candv[h][p] = v[j]; candi[h][p] = (unsigned)(base + lane + 64 * j); }
      }
    }
    unsigned c = cnt_s[h];
    for (unsigned p = c + (unsigned)lane; p < CAND; p += 64u) {
      candv[h][p] = -INFINITY; candi[h][p] = 0x7F000000u + p;
    }
    if (lane < CAND) {
      size_t o = (((size_t)(b * NH + h)) * NCHUNK + chunk) * CAND + lane;
      cv_ws[o] = candv[h][lane];
      ci_ws[o] = candi[h][lane];
    }
  }
}

// Kernel 3: per (b,h): stage-1 per-wave top-[32,48] supersets (shfl-only),
// stage-2 rank-based exact sorted top-32 over <=192 survivors, then softmax +
// gather. (known-good since R4)
__global__ __launch_bounds__(256) void k_final(
    const float* __restrict__ mem, const float* __restrict__ cv_ws,
    const unsigned* __restrict__ ci_ws, float* __restrict__ dout) {
  const int bh = blockIdx.x;
  const int b = bh >> 3;
  const int t = threadIdx.x;
  const int lane = t & 63, w = t >> 6;  // 4 waves

  __shared__ float cv[STAGE1];
  __shared__ unsigned ci[STAGE1];
  __shared__ unsigned cnt_s[4];
  __shared__ float fv[NK];
  __shared__ unsigned fi[NK];
  __shared__ float wts[NK];
  __shared__ unsigned widx[NK];

  const float* CV = cv_ws + (size_t)bh * NCTOT;
  const unsigned* CI = ci_ws + (size_t)bh * NCTOT;

  float v[FPT];
  unsigned vi[FPT];
  #pragma unroll
  for (int i = 0; i < FPT; ++i) {
    v[i] = CV[i * 256 + t];
    vi[i] = CI[i * 256 + t];
  }

  // wave-local range (exclude -INF pads from min)
  float mx = -INFINITY, mn = INFINITY;
  #pragma unroll
  for (int i = 0; i < FPT; ++i) {
    mx = fmaxf(mx, v[i]);
    if (v[i] > -1e37f) mn = fminf(mn, v[i]);
  }
  #pragma unroll
  for (int off = 32; off >= 1; off >>= 1) {
    mx = fmaxf(mx, __shfl_xor(mx, off, 64));
    mn = fminf(mn, __shfl_xor(mn, off, 64));
  }

  // wave-local binary search: count(>T) in [NK, CAND] over this wave's 1536
  float lo = mn - 1.0f, hi = mx, T = lo;
  bool found = false;
  for (int it = 0; it < 48; ++it) {
    float mid = 0.5f * (lo + hi);
    if (!(mid > lo && mid < hi)) break;
    unsigned c = 0;
    #pragma unroll
    for (int i = 0; i < FPT; ++i) c += (v[i] > mid) ? 1u : 0u;
    #pragma unroll
    for (int off = 32; off >= 1; off >>= 1) c += __shfl_xor(c, off, 64);
    if (c >= NK) {
      lo = mid;
      if (c <= CAND) { T = mid; found = true; break; }
    } else {
      hi = mid;
    }
  }
  if (!found) T = lo;

  if (lane == 0) cnt_s[w] = 0u;
  #pragma unroll
  for (int i = 0; i < FPT; ++i) {
    if (v[i] > T) {
      unsigned p = atomicAdd(&cnt_s[w], 1u);
      if (p < CAND) { cv[w * CAND + p] = v[i]; ci[w * CAND + p] = vi[i]; }
    }
  }
  {
    unsigned c = cnt_s[w];
    for (unsigned p = c + (unsigned)lane; p < CAND; p += 64u) {
      cv[w * CAND + p] = -INFINITY;
      ci[w * CAND + p] = 0x7F100000u + w * CAND + p;
    }
  }
  __syncthreads();

  // stage 2: exact rank (val desc, idx asc); top-32 land sorted in fv/fi
  if (t < STAGE1) {
    float myv = cv[t];
    unsigned myi = ci[t];
    int rank = 0;
    for (int j = 0; j < STAGE1; ++j) {
      float vj = cv[j];
      unsigned ij = ci[j];
      rank += ((vj > myv) || (vj == myv && ij < myi)) ? 1 : 0;
    }
    if (rank < NK) { fv[rank] = myv; fi[rank] = myi; }
  }
  __syncthreads();

  // softmax over the sorted top-32 (fv[0] is the max)
  if (t < NK) {
    float e = expf(fv[t] - fv[0]);
    float sum = e;
    #pragma unroll
    for (int off = 16; off >= 1; off >>= 1) sum += __shfl_xor(sum, off, 32);
    float wgt = e / sum;
    wts[t] = wgt;
    widx[t] = fi[t];
    dout[OFF_W + bh * NK + t] = wgt;
    dout[OFF_I + bh * NK + t] = (float)fi[t];
  }
  __syncthreads();

  // memory_reads[b,h,m] = sum_k w_k * mem[b, idx_k, m]
  if (t < NM) {
    float acc = 0.f;
    #pragma unroll 8
    for (int k = 0; k < NK; ++k) {
      unsigned gi = widx[k] < NR ? widx[k] : 0u;  // defensive clamp
      acc += wts[k] * mem[((size_t)b * NR + gi) * NM + t];
    }
    dout[OFF_READS + bh * NM + t] = acc;
  }
}

extern "C" void kernel_launch(void* const* d_in, const int* in_sizes, int n_in,
                              void* d_out, int out_size, void* d_ws, size_t ws_size,
                              hipStream_t stream) {
  const float* x    = (const float*)d_in[0];  // read_inputs (16,512)
  const float* mem  = (const float*)d_in[1];  // mem_state (16,65536,64)
  const float* W    = (const float*)d_in[2];  // (520,512)
  const float* bias = (const float*)d_in[3];  // (520,)
  float* out = (float*)d_out;

  char* ws = (char*)d_ws;
  float* sk_ws    = (float*)ws;                   // 32 KB
  float* str_ws   = (float*)(ws + 32768);         // 512 B
  const size_t cand_bytes = (size_t)NB * NH * NCTOT * 4;  // 3.15 MB
  float* cv_ws    = (float*)(ws + 65536);
  unsigned* ci_ws = (unsigned*)(ws + 65536 + cand_bytes);

  hipLaunchKernelGGL(k_prep, dim3(NB * 9), dim3(512), 0, stream, x, W, bias, sk_ws, str_ws, out);
  hipLaunchKernelGGL(k_score, dim3(NB * NCHUNK), dim3(512), 0, stream, mem, sk_ws, str_ws, cv_ws, ci_ws);
  hipLaunchKernelGGL(k_final, dim3(NB * NH), dim3(256), 0, stream, mem, cv_ws, ci_ws, out);
}